// Round 1
// baseline (2445.448 us; speedup 1.0000x reference)
//
#include <hip/hip_runtime.h>
#include <math.h>

// SelfAttention: B=4, S=2048, D=1024, fp32 in/out.
// Round 1: correctness-first all-fp32 tiled baseline.
//   K1 (gemm_f32<1>, NT): Q = X @ Wq^T, K = X @ Wk^T   (full, 8192x1024)
//   per batch b:
//     V_b = X_b @ Wv^T          (2048x1024)
//     L_b = Q_b @ K_b^T         (2048x2048)
//     softmax rows of L_b
//     O_b = L_b @ V_b           (gemm_f32<0>, NN) -> d_out
// Workspace (floats): Q[8.39M] K[8.39M] V_b[2.10M] L_b[4.19M] = ~88 MB.

#define TILE_BM 128
#define TILE_BN 128
#define TILE_BK 16

// C[M,N] = A[M,K] * op(B); TRANS_B=1: B is [N,K] (NT), TRANS_B=0: B is [K,N] (NN).
// Requires M,N % 128 == 0, K % 16 == 0. 256 threads, 8x8 per thread
// (split as 2x2 blocks of 4x4 at +0/+64 offsets for conflict-free LDS reads).
template <int TRANS_B>
__global__ __launch_bounds__(256) void gemm_f32(
    const float* __restrict__ A, const float* __restrict__ B,
    float* __restrict__ C, int M, int N, int Kd, int lda, int ldb, int ldc) {
  __shared__ float As[TILE_BK][TILE_BM];
  __shared__ float Bs[TILE_BK][TILE_BN];

  const int tid = threadIdx.x;
  const int tx = tid & 15;         // 0..15 -> col groups
  const int ty = tid >> 4;         // 0..15 -> row groups
  const int m0 = blockIdx.y * TILE_BM;
  const int n0 = blockIdx.x * TILE_BN;

  // loader mapping for NT-style tiles (A always; B when TRANS_B)
  const int lrow = tid >> 1;       // 0..127
  const int lkp = (tid & 1) * 8;   // 0 or 8
  // loader mapping for NN B tile
  const int bkr = tid >> 4;        // 0..15 (k within tile)
  const int bnc = tx * 4;          // 0..60

  float acc[8][8];
#pragma unroll
  for (int i = 0; i < 8; i++)
#pragma unroll
    for (int j = 0; j < 8; j++) acc[i][j] = 0.f;

  for (int k0 = 0; k0 < Kd; k0 += TILE_BK) {
    // ---- global loads (issue before barrier) ----
    const float4 av0 = *(const float4*)(A + (size_t)(m0 + lrow) * lda + k0 + lkp);
    const float4 av1 = *(const float4*)(A + (size_t)(m0 + lrow) * lda + k0 + lkp + 4);
    float4 bv0, bv1;
    if (TRANS_B) {
      bv0 = *(const float4*)(B + (size_t)(n0 + lrow) * ldb + k0 + lkp);
      bv1 = *(const float4*)(B + (size_t)(n0 + lrow) * ldb + k0 + lkp + 4);
    } else {
      bv0 = *(const float4*)(B + (size_t)(k0 + bkr) * ldb + n0 + bnc);
      bv1 = *(const float4*)(B + (size_t)(k0 + bkr) * ldb + n0 + bnc + 64);
    }

    __syncthreads();  // previous iter done reading LDS
    // ---- LDS stores (A transposed to [k][m]) ----
#pragma unroll
    for (int i = 0; i < 4; i++) As[lkp + i][lrow] = (&av0.x)[i];
#pragma unroll
    for (int i = 0; i < 4; i++) As[lkp + 4 + i][lrow] = (&av1.x)[i];
    if (TRANS_B) {
#pragma unroll
      for (int i = 0; i < 4; i++) Bs[lkp + i][lrow] = (&bv0.x)[i];
#pragma unroll
      for (int i = 0; i < 4; i++) Bs[lkp + 4 + i][lrow] = (&bv1.x)[i];
    } else {
      *(float4*)&Bs[bkr][bnc] = bv0;
      *(float4*)&Bs[bkr][bnc + 64] = bv1;
    }
    __syncthreads();

    // ---- compute ----
#pragma unroll
    for (int kk = 0; kk < TILE_BK; kk++) {
      const float4 a0 = *(const float4*)&As[kk][ty * 4];
      const float4 a1 = *(const float4*)&As[kk][64 + ty * 4];
      const float4 b0 = *(const float4*)&Bs[kk][tx * 4];
      const float4 b1 = *(const float4*)&Bs[kk][64 + tx * 4];
      const float a[8] = {a0.x, a0.y, a0.z, a0.w, a1.x, a1.y, a1.z, a1.w};
      const float b[8] = {b0.x, b0.y, b0.z, b0.w, b1.x, b1.y, b1.z, b1.w};
#pragma unroll
      for (int i = 0; i < 8; i++)
#pragma unroll
        for (int j = 0; j < 8; j++) acc[i][j] = fmaf(a[i], b[j], acc[i][j]);
    }
  }

  // ---- epilogue ----
#pragma unroll
  for (int rb = 0; rb < 2; rb++)
#pragma unroll
    for (int ri = 0; ri < 4; ri++) {
      const int row = m0 + rb * 64 + ty * 4 + ri;
      float4 v0, v1;
      v0.x = acc[rb * 4 + ri][0]; v0.y = acc[rb * 4 + ri][1];
      v0.z = acc[rb * 4 + ri][2]; v0.w = acc[rb * 4 + ri][3];
      v1.x = acc[rb * 4 + ri][4]; v1.y = acc[rb * 4 + ri][5];
      v1.z = acc[rb * 4 + ri][6]; v1.w = acc[rb * 4 + ri][7];
      *(float4*)(C + (size_t)row * ldc + n0 + tx * 4) = v0;
      *(float4*)(C + (size_t)row * ldc + n0 + 64 + tx * 4) = v1;
    }
}

// One block per row of 2048; softmax in place. 256 threads, 8 elems/thread.
__global__ __launch_bounds__(256) void softmax2048(float* __restrict__ L) {
  float* p = L + (size_t)blockIdx.x * 2048;
  const int t = threadIdx.x;
  const int wv = t >> 6, ln = t & 63;

  float4 x0 = *(const float4*)(p + t * 4);
  float4 x1 = *(const float4*)(p + 1024 + t * 4);

  float m = fmaxf(fmaxf(fmaxf(x0.x, x0.y), fmaxf(x0.z, x0.w)),
                  fmaxf(fmaxf(x1.x, x1.y), fmaxf(x1.z, x1.w)));
#pragma unroll
  for (int off = 32; off; off >>= 1) m = fmaxf(m, __shfl_xor(m, off));
  __shared__ float redm[4];
  __shared__ float reds[4];
  if (ln == 0) redm[wv] = m;
  __syncthreads();
  m = fmaxf(fmaxf(redm[0], redm[1]), fmaxf(redm[2], redm[3]));

  float e[8];
  e[0] = __expf(x0.x - m); e[1] = __expf(x0.y - m);
  e[2] = __expf(x0.z - m); e[3] = __expf(x0.w - m);
  e[4] = __expf(x1.x - m); e[5] = __expf(x1.y - m);
  e[6] = __expf(x1.z - m); e[7] = __expf(x1.w - m);
  float s = e[0] + e[1] + e[2] + e[3] + e[4] + e[5] + e[6] + e[7];
#pragma unroll
  for (int off = 32; off; off >>= 1) s += __shfl_xor(s, off);
  if (ln == 0) reds[wv] = s;
  __syncthreads();
  const float inv = 1.f / (reds[0] + reds[1] + reds[2] + reds[3]);

  float4 o0, o1;
  o0.x = e[0] * inv; o0.y = e[1] * inv; o0.z = e[2] * inv; o0.w = e[3] * inv;
  o1.x = e[4] * inv; o1.y = e[5] * inv; o1.z = e[6] * inv; o1.w = e[7] * inv;
  *(float4*)(p + t * 4) = o0;
  *(float4*)(p + 1024 + t * 4) = o1;
}

extern "C" void kernel_launch(void* const* d_in, const int* in_sizes, int n_in,
                              void* d_out, int out_size, void* d_ws, size_t ws_size,
                              hipStream_t stream) {
  constexpr int Bn = 4, S = 2048, D = 1024;
  constexpr size_t TOK = (size_t)Bn * S;        // 8192
  const float* X = (const float*)d_in[0];
  const float* Wq = (const float*)d_in[1];
  const float* Wk = (const float*)d_in[2];
  const float* Wv = (const float*)d_in[3];
  float* out = (float*)d_out;

  float* ws = (float*)d_ws;
  float* Qb = ws;                                // 8192*1024
  float* Kb = Qb + TOK * D;                      // 8192*1024
  float* Vb = Kb + TOK * D;                      // 2048*1024 (per batch)
  float* Lb = Vb + (size_t)S * D;                // 2048*2048 (per batch)

  const dim3 blk(256);
  // Q, K projections (full)
  {
    dim3 grid(D / TILE_BN, TOK / TILE_BM);
    gemm_f32<1><<<grid, blk, 0, stream>>>(X, Wq, Qb, (int)TOK, D, D, D, D, D);
    gemm_f32<1><<<grid, blk, 0, stream>>>(X, Wk, Kb, (int)TOK, D, D, D, D, D);
  }
  for (int b = 0; b < Bn; b++) {
    const size_t boff = (size_t)b * S * D;       // token offset into X/Q/K/out
    // V_b
    {
      dim3 grid(D / TILE_BN, S / TILE_BM);
      gemm_f32<1><<<grid, blk, 0, stream>>>(X + boff, Wv, Vb, S, D, D, D, D, D);
    }
    // L_b = Q_b @ K_b^T
    {
      dim3 grid(S / TILE_BN, S / TILE_BM);
      gemm_f32<1><<<grid, blk, 0, stream>>>(Qb + boff, Kb + boff, Lb, S, S, D, D, D, S);
    }
    // softmax rows
    softmax2048<<<dim3(S), blk, 0, stream>>>(Lb);
    // O_b = P @ V_b
    {
      dim3 grid(D / TILE_BN, S / TILE_BM);
      gemm_f32<0><<<grid, blk, 0, stream>>>(Lb, Vb, out + boff, S, D, S, S, D, D);
    }
  }
}

// Round 2
// 702.635 us; speedup vs baseline: 3.4804x; 3.4804x over previous
//
#include <hip/hip_runtime.h>
#include <math.h>

// SelfAttention B=4,S=2048,D=1024 fp32. Round 2: split-bf16 MFMA.
// Precision plan: X,W,Q,K kept as (hi,lo) bf16 pairs; GEMMs on the logit
// chain run 3-pass (hh+hl+lh) MFMA -> logit err ~3e-4. P,V plain bf16.
// All GEMMs are NT: C[m,n] = sum_k A[m,k]*B[n,k]:
//   Qh,Ql = X @ Wq^T   (SPLIT in, split-bf16 out)
//   Kh,Kl = X @ Wk^T
//   VT    = Wv @ X^T   (plain, bf16 out)   [1024 x 2048 per batch]
//   L     = Q @ K^T    (SPLIT in, f32 out)
//   P     = softmax(L) (f32 in, bf16 out)
//   O     = P @ VT^T   (plain, f32 out)

typedef unsigned short u16;
typedef __attribute__((ext_vector_type(8))) short bf16x8;
typedef __attribute__((ext_vector_type(4))) float f32x4;

__device__ __forceinline__ u16 f2bf(float x) {
  unsigned u = __float_as_uint(x);
  unsigned r = (u + 0x7fffu + ((u >> 16) & 1u)) >> 16;
  return (u16)r;
}
__device__ __forceinline__ float bf2f(u16 h) {
  return __uint_as_float((unsigned)h << 16);
}

__device__ __forceinline__ void gload_lds16(const u16* g, u16* l) {
  __builtin_amdgcn_global_load_lds(
      (const __attribute__((address_space(1))) unsigned int*)(g),
      (__attribute__((address_space(3))) unsigned int*)(l), 16, 0, 0);
}

// fp32 -> (hi bf16, lo bf16), vectorized, grid-stride
__global__ __launch_bounds__(256) void split_f32_kernel(
    const float* __restrict__ in, u16* __restrict__ hi, u16* __restrict__ lo,
    long long n) {
  long long i = ((long long)blockIdx.x * 256 + threadIdx.x) * 4;
  const long long step = (long long)gridDim.x * 256 * 4;
  for (; i < n; i += step) {
    float4 x = *(const float4*)(in + i);
    float xs[4] = {x.x, x.y, x.z, x.w};
    ushort4 h, l;
    u16 hv[4], lv[4];
#pragma unroll
    for (int j = 0; j < 4; j++) {
      hv[j] = f2bf(xs[j]);
      lv[j] = f2bf(xs[j] - bf2f(hv[j]));
    }
    h.x = hv[0]; h.y = hv[1]; h.z = hv[2]; h.w = hv[3];
    l.x = lv[0]; l.y = lv[1]; l.z = lv[2]; l.w = lv[3];
    *(ushort4*)(hi + i) = h;
    *(ushort4*)(lo + i) = l;
  }
}

#define BM 128
#define BN 128
#define BK 32

// NT GEMM, 256 thr = 4 waves (2x2), each wave 64x64 = 4x4 frags of 16x16x32.
// LDS tiles use subtiled layout: elem(row,k) at ushort off
//   (row>>4)*512 + ((k>>3)&3)*128 + (row&15)*8 + (k&7)
// -> fragment ds_read_b128 is lane-linear (conflict-free) and global_load_lds
//    dest is linear in tid (chunk c=tid -> row=(c>>6)*16+(c&15), k=((c>>4)&3)*8).
// SPLIT: 3-pass hh+hl+lh. STORE: 0=f32, 1=split bf16 (Ch,Cl), 2=bf16 (Ch).
template <int SPLIT, int STORE>
__global__ __launch_bounds__(256) void gemm_nt(
    const u16* __restrict__ Ah, const u16* __restrict__ Al,
    const u16* __restrict__ Bh, const u16* __restrict__ Bl,
    float* __restrict__ Cf, u16* __restrict__ Ch, u16* __restrict__ Cl,
    int M, int N, int K, int lda, int ldb, int ldc,
    long long sA, long long sB, long long sC) {
  const int z = blockIdx.z;
  Ah += (long long)z * sA;
  Bh += (long long)z * sB;
  if (SPLIT) { Al += (long long)z * sA; Bl += (long long)z * sB; }

  __shared__ u16 lds[(SPLIT ? 4 : 2) * 4096];
  u16* As_h = lds;
  u16* Bs_h = lds + 4096;
  u16* As_l = SPLIT ? (lds + 8192) : lds;
  u16* Bs_l = SPLIT ? (lds + 12288) : lds;

  const int tid = threadIdx.x;
  const int ln = tid & 63;
  const int wid = tid >> 6;
  const int wm = (wid >> 1) * 64;
  const int wn = (wid & 1) * 64;
  const int m0 = blockIdx.y * BM;
  const int n0 = blockIdx.x * BN;

  const int c0 = tid, c1 = tid + 256;
  const int row0 = ((c0 >> 6) << 4) + (c0 & 15), col0 = ((c0 >> 4) & 3) * 8;
  const int row1 = ((c1 >> 6) << 4) + (c1 & 15), col1 = ((c1 >> 4) & 3) * 8;

  f32x4 acc[4][4];
  const f32x4 zero = {0.f, 0.f, 0.f, 0.f};
#pragma unroll
  for (int i = 0; i < 4; i++)
#pragma unroll
    for (int j = 0; j < 4; j++) acc[i][j] = zero;

  const int rbm = wm >> 4;
  const int rbn = wn >> 4;
  const int fo = ln * 8;

  for (int k0 = 0; k0 < K; k0 += BK) {
    // ---- stage (global -> LDS, linear dest, remapped source) ----
    {
      const u16* Ab = Ah + (size_t)m0 * lda + k0;
      const u16* Bb = Bh + (size_t)n0 * ldb + k0;
      gload_lds16(Ab + (size_t)row0 * lda + col0, As_h + c0 * 8);
      gload_lds16(Ab + (size_t)row1 * lda + col1, As_h + c1 * 8);
      gload_lds16(Bb + (size_t)row0 * ldb + col0, Bs_h + c0 * 8);
      gload_lds16(Bb + (size_t)row1 * ldb + col1, Bs_h + c1 * 8);
      if (SPLIT) {
        const u16* Abl = Al + (size_t)m0 * lda + k0;
        const u16* Bbl = Bl + (size_t)n0 * ldb + k0;
        gload_lds16(Abl + (size_t)row0 * lda + col0, As_l + c0 * 8);
        gload_lds16(Abl + (size_t)row1 * lda + col1, As_l + c1 * 8);
        gload_lds16(Bbl + (size_t)row0 * ldb + col0, Bs_l + c0 * 8);
        gload_lds16(Bbl + (size_t)row1 * ldb + col1, Bs_l + c1 * 8);
      }
    }
    __syncthreads();  // drains vmcnt -> LDS visible

    // ---- fragments + MFMA ----
    bf16x8 ah[4], bh[4], al[4], bl[4];
#pragma unroll
    for (int i = 0; i < 4; i++) {
      ah[i] = *(const bf16x8*)(As_h + (rbm + i) * 512 + fo);
      bh[i] = *(const bf16x8*)(Bs_h + (rbn + i) * 512 + fo);
    }
    if (SPLIT) {
#pragma unroll
      for (int i = 0; i < 4; i++) {
        al[i] = *(const bf16x8*)(As_l + (rbm + i) * 512 + fo);
        bl[i] = *(const bf16x8*)(Bs_l + (rbn + i) * 512 + fo);
      }
    }
#pragma unroll
    for (int mi = 0; mi < 4; mi++)
#pragma unroll
      for (int ni = 0; ni < 4; ni++)
        acc[mi][ni] = __builtin_amdgcn_mfma_f32_16x16x32_bf16(
            ah[mi], bh[ni], acc[mi][ni], 0, 0, 0);
    if (SPLIT) {
#pragma unroll
      for (int mi = 0; mi < 4; mi++)
#pragma unroll
        for (int ni = 0; ni < 4; ni++)
          acc[mi][ni] = __builtin_amdgcn_mfma_f32_16x16x32_bf16(
              ah[mi], bl[ni], acc[mi][ni], 0, 0, 0);
#pragma unroll
      for (int mi = 0; mi < 4; mi++)
#pragma unroll
        for (int ni = 0; ni < 4; ni++)
          acc[mi][ni] = __builtin_amdgcn_mfma_f32_16x16x32_bf16(
              al[mi], bh[ni], acc[mi][ni], 0, 0, 0);
    }
    __syncthreads();  // all waves done reading before next overwrite
  }

  // ---- epilogue: C/D layout col=lane&15, row=(lane>>4)*4+reg ----
  const int orow = (ln >> 4) * 4;
  const int ocol = ln & 15;
#pragma unroll
  for (int mi = 0; mi < 4; mi++)
#pragma unroll
    for (int ni = 0; ni < 4; ni++) {
      const int rbase = m0 + wm + mi * 16 + orow;
      const int cc = n0 + wn + ni * 16 + ocol;
#pragma unroll
      for (int i = 0; i < 4; i++) {
        const float v = acc[mi][ni][i];
        const long long off = (long long)(rbase + i) * ldc + cc + (long long)z * sC;
        if (STORE == 0) {
          Cf[off] = v;
        } else if (STORE == 1) {
          const u16 h = f2bf(v);
          Ch[off] = h;
          Cl[off] = f2bf(v - bf2f(h));
        } else {
          Ch[off] = f2bf(v);
        }
      }
    }
}

// row softmax: L fp32 [2048] -> P bf16 [2048]; one block per row
__global__ __launch_bounds__(256) void softmax_bf16(
    const float* __restrict__ L, u16* __restrict__ P) {
  const float* p = L + (size_t)blockIdx.x * 2048;
  u16* q = P + (size_t)blockIdx.x * 2048;
  const int t = threadIdx.x;
  const int wv = t >> 6, lnn = t & 63;

  float4 x0 = *(const float4*)(p + t * 4);
  float4 x1 = *(const float4*)(p + 1024 + t * 4);

  float m = fmaxf(fmaxf(fmaxf(x0.x, x0.y), fmaxf(x0.z, x0.w)),
                  fmaxf(fmaxf(x1.x, x1.y), fmaxf(x1.z, x1.w)));
#pragma unroll
  for (int off = 32; off; off >>= 1) m = fmaxf(m, __shfl_xor(m, off));
  __shared__ float redm[4];
  __shared__ float reds[4];
  if (lnn == 0) redm[wv] = m;
  __syncthreads();
  m = fmaxf(fmaxf(redm[0], redm[1]), fmaxf(redm[2], redm[3]));

  float e[8];
  e[0] = __expf(x0.x - m); e[1] = __expf(x0.y - m);
  e[2] = __expf(x0.z - m); e[3] = __expf(x0.w - m);
  e[4] = __expf(x1.x - m); e[5] = __expf(x1.y - m);
  e[6] = __expf(x1.z - m); e[7] = __expf(x1.w - m);
  float s = e[0] + e[1] + e[2] + e[3] + e[4] + e[5] + e[6] + e[7];
#pragma unroll
  for (int off = 32; off; off >>= 1) s += __shfl_xor(s, off);
  if (lnn == 0) reds[wv] = s;
  __syncthreads();
  const float inv = 1.f / (reds[0] + reds[1] + reds[2] + reds[3]);

  ushort4 o0, o1;
  o0.x = f2bf(e[0] * inv); o0.y = f2bf(e[1] * inv);
  o0.z = f2bf(e[2] * inv); o0.w = f2bf(e[3] * inv);
  o1.x = f2bf(e[4] * inv); o1.y = f2bf(e[5] * inv);
  o1.z = f2bf(e[6] * inv); o1.w = f2bf(e[7] * inv);
  *(ushort4*)(q + t * 4) = o0;
  *(ushort4*)(q + 1024 + t * 4) = o1;
}

extern "C" void kernel_launch(void* const* d_in, const int* in_sizes, int n_in,
                              void* d_out, int out_size, void* d_ws, size_t ws_size,
                              hipStream_t stream) {
  constexpr int Bn = 4, S = 2048, D = 1024;
  constexpr long long TOK = (long long)Bn * S;  // 8192
  const float* X = (const float*)d_in[0];
  const float* Wq = (const float*)d_in[1];
  const float* Wk = (const float*)d_in[2];
  const float* Wv = (const float*)d_in[3];
  float* out = (float*)d_out;

  char* w = (char*)d_ws;
  auto alloc_us = [&](long long n) { u16* p = (u16*)w; w += n * 2; return p; };

  u16* Xh = alloc_us(TOK * D);
  u16* Xl = alloc_us(TOK * D);
  u16* Wqh = alloc_us((long long)D * D);
  u16* Wql = alloc_us((long long)D * D);
  u16* Wkh = alloc_us((long long)D * D);
  u16* Wkl = alloc_us((long long)D * D);
  u16* Wvh = alloc_us((long long)D * D);  // Wv lo is never used (VT is 1-pass)

  const bool full = ws_size >= (size_t)154 * 1024 * 1024;
  const long long PR = full ? TOK : S;       // projection rows resident
  u16* Qh = alloc_us(PR * D);
  u16* Ql = alloc_us(PR * D);
  u16* Kh = alloc_us(PR * D);
  u16* Kl = alloc_us(PR * D);
  u16* VTh = alloc_us((full ? 4 : 1) * (long long)D * S);
  float* Lb = (float*)w; w += (long long)S * S * 4;
  u16* Ph = alloc_us((long long)S * S);

  const dim3 blk(256);
  // conversions (Wv's lo goes into Ph as scratch; overwritten later)
  split_f32_kernel<<<2048, blk, 0, stream>>>(X, Xh, Xl, TOK * D);
  split_f32_kernel<<<512, blk, 0, stream>>>(Wq, Wqh, Wql, (long long)D * D);
  split_f32_kernel<<<512, blk, 0, stream>>>(Wk, Wkh, Wkl, (long long)D * D);
  split_f32_kernel<<<512, blk, 0, stream>>>(Wv, Wvh, Ph, (long long)D * D);

  if (full) {
    // Q,K projections over all tokens: M=8192,N=1024,K=1024
    gemm_nt<1, 1><<<dim3(D / BN, TOK / BM), blk, 0, stream>>>(
        Xh, Xl, Wqh, Wql, nullptr, Qh, Ql, (int)TOK, D, D, D, D, D, 0, 0, 0);
    gemm_nt<1, 1><<<dim3(D / BN, TOK / BM), blk, 0, stream>>>(
        Xh, Xl, Wkh, Wkl, nullptr, Kh, Kl, (int)TOK, D, D, D, D, D, 0, 0, 0);
    // VT[z] = Wv @ X_z^T : M=1024,N=2048,K=1024, z-batched
    gemm_nt<0, 2><<<dim3(S / BN, D / BM, Bn), blk, 0, stream>>>(
        Wvh, nullptr, Xh, nullptr, nullptr, VTh, nullptr, D, S, D, D, D, S,
        0, (long long)S * D, (long long)D * S);
    for (int b = 0; b < Bn; b++) {
      const long long qo = (long long)b * S * D;
      gemm_nt<1, 0><<<dim3(S / BN, S / BM), blk, 0, stream>>>(
          Qh + qo, Ql + qo, Kh + qo, Kl + qo, Lb, nullptr, nullptr,
          S, S, D, D, D, S, 0, 0, 0);
      softmax_bf16<<<dim3(S), blk, 0, stream>>>(Lb, Ph);
      gemm_nt<0, 0><<<dim3(D / BN, S / BM), blk, 0, stream>>>(
          Ph, nullptr, VTh + (long long)b * D * S, nullptr, out + qo,
          nullptr, nullptr, S, D, S, S, S, D, 0, 0, 0);
    }
  } else {
    for (int b = 0; b < Bn; b++) {
      const long long xo = (long long)b * S * D;
      gemm_nt<1, 1><<<dim3(D / BN, S / BM), blk, 0, stream>>>(
          Xh + xo, Xl + xo, Wqh, Wql, nullptr, Qh, Ql, S, D, D, D, D, D, 0, 0, 0);
      gemm_nt<1, 1><<<dim3(D / BN, S / BM), blk, 0, stream>>>(
          Xh + xo, Xl + xo, Wkh, Wkl, nullptr, Kh, Kl, S, D, D, D, D, D, 0, 0, 0);
      gemm_nt<0, 2><<<dim3(S / BN, D / BM), blk, 0, stream>>>(
          Wvh, nullptr, Xh + xo, nullptr, nullptr, VTh, nullptr,
          D, S, D, D, D, S, 0, 0, 0);
      gemm_nt<1, 0><<<dim3(S / BN, S / BM), blk, 0, stream>>>(
          Qh, Ql, Kh, Kl, Lb, nullptr, nullptr, S, S, D, D, D, S, 0, 0, 0);
      softmax_bf16<<<dim3(S), blk, 0, stream>>>(Lb, Ph);
      gemm_nt<0, 0><<<dim3(D / BN, S / BM), blk, 0, stream>>>(
          Ph, nullptr, VTh, nullptr, out + xo, nullptr, nullptr,
          S, D, S, S, S, D, 0, 0, 0);
    }
  }
}

// Round 3
// 590.084 us; speedup vs baseline: 4.1442x; 1.1907x over previous
//
#include <hip/hip_runtime.h>
#include <math.h>

// SelfAttention B=4,S=2048,D=1024 fp32. Round 3: concat-K split + batched grids.
// All GEMMs are plain-bf16 NT over NSEG K-segments (split-fp32 numerics via
// segment pointers): C[m,n] = sum_seg sum_k Aseg[m,k]*Bseg[n,k].
//   QK-proj (fused): [Q|K](8192x2048) = segs (Xh,Xh,Xl)x(Wch,Wcl,Wch), split store
//   VT (z=4): VT[d,s] = Wvh . Xh^T, bf16 store
//   L (z-batch): segs (Qh,Qh,Ql)x(Kh,Kl,Kh) via QKh/QKl col-halves, f32 store
//   softmax in-place: P(bf16) overwrites L rows (row stride stays 4096 u16)
//   O = P . VT^T, f32 store to d_out

typedef unsigned short u16;
typedef __attribute__((ext_vector_type(8))) short bf16x8;
typedef __attribute__((ext_vector_type(4))) float f32x4;

__device__ __forceinline__ u16 f2bf(float x) {
  unsigned u = __float_as_uint(x);
  unsigned r = (u + 0x7fffu + ((u >> 16) & 1u)) >> 16;
  return (u16)r;
}
__device__ __forceinline__ float bf2f(u16 h) {
  return __uint_as_float((unsigned)h << 16);
}

__device__ __forceinline__ void gload_lds16(const u16* g, u16* l) {
  __builtin_amdgcn_global_load_lds(
      (const __attribute__((address_space(1))) unsigned int*)(g),
      (__attribute__((address_space(3))) unsigned int*)(l), 16, 0, 0);
}

// fp32 -> hi bf16 (+ optional lo bf16), grid-stride, vectorized
template <bool LO>
__global__ __launch_bounds__(256) void split_f32_kernel(
    const float* __restrict__ in, u16* __restrict__ hi, u16* __restrict__ lo,
    long long n) {
  long long i = ((long long)blockIdx.x * 256 + threadIdx.x) * 4;
  const long long step = (long long)gridDim.x * 256 * 4;
  for (; i < n; i += step) {
    float4 x = *(const float4*)(in + i);
    float xs[4] = {x.x, x.y, x.z, x.w};
    u16 hv[4], lv[4];
#pragma unroll
    for (int j = 0; j < 4; j++) {
      hv[j] = f2bf(xs[j]);
      if (LO) lv[j] = f2bf(xs[j] - bf2f(hv[j]));
    }
    ushort4 h;
    h.x = hv[0]; h.y = hv[1]; h.z = hv[2]; h.w = hv[3];
    *(ushort4*)(hi + i) = h;
    if (LO) {
      ushort4 l;
      l.x = lv[0]; l.y = lv[1]; l.z = lv[2]; l.w = lv[3];
      *(ushort4*)(lo + i) = l;
    }
  }
}

#define BM 128
#define BN 128
#define BK 32

// Plain-bf16 NT GEMM over NSEG K-segments. 256 thr = 4 waves (2x2),
// each wave 64x64 = 4x4 frags of mfma_f32_16x16x32_bf16.
// LDS subtiled layout: elem(row,k) at u16 off (row>>4)*512+((k>>3)&3)*128+(row&15)*8+(k&7)
//  -> ds_read_b128 fragment reads lane-linear (conflict-free), global_load_lds
//     dest linear in tid (rule #21: remapped global source, linear LDS dest).
// STORE: 0 = f32 Cf, 1 = split bf16 (Ch,Cl), 2 = bf16 (Ch).
template <int NSEG, int STORE>
__global__ __launch_bounds__(256) void gemm_nt(
    const u16* __restrict__ A0, const u16* __restrict__ A1,
    const u16* __restrict__ A2, const u16* __restrict__ B0,
    const u16* __restrict__ B1, const u16* __restrict__ B2,
    float* __restrict__ Cf, u16* __restrict__ Ch, u16* __restrict__ Cl,
    int Kseg, int lda, int ldb, int ldc,
    long long sA, long long sB, long long sC) {
  __shared__ u16 As[4096];
  __shared__ u16 Bs[4096];

  const int tid = threadIdx.x;
  const int ln = tid & 63;
  const int wid = tid >> 6;
  const int wm = (wid >> 1) * 64;
  const int wn = (wid & 1) * 64;
  const int m0 = blockIdx.y * BM;
  const int n0 = blockIdx.x * BN;
  const int z = blockIdx.z;

  const int c0 = tid, c1 = tid + 256;
  const int row0 = ((c0 >> 6) << 4) + (c0 & 15), col0 = ((c0 >> 4) & 3) * 8;
  const int row1 = ((c1 >> 6) << 4) + (c1 & 15), col1 = ((c1 >> 4) & 3) * 8;

  f32x4 acc[4][4];
  const f32x4 zero = {0.f, 0.f, 0.f, 0.f};
#pragma unroll
  for (int i = 0; i < 4; i++)
#pragma unroll
    for (int j = 0; j < 4; j++) acc[i][j] = zero;

  const int rbm = wm >> 4;
  const int rbn = wn >> 4;
  const int fo = ln * 8;

#pragma unroll
  for (int seg = 0; seg < NSEG; ++seg) {
    const u16* Ab = (seg == 0 ? A0 : (seg == 1 ? A1 : A2)) +
                    (long long)z * sA + (size_t)m0 * lda;
    const u16* Bb = (seg == 0 ? B0 : (seg == 1 ? B1 : B2)) +
                    (long long)z * sB + (size_t)n0 * ldb;
    for (int k0 = 0; k0 < Kseg; k0 += BK) {
      gload_lds16(Ab + (size_t)row0 * lda + k0 + col0, As + c0 * 8);
      gload_lds16(Ab + (size_t)row1 * lda + k0 + col1, As + c1 * 8);
      gload_lds16(Bb + (size_t)row0 * ldb + k0 + col0, Bs + c0 * 8);
      gload_lds16(Bb + (size_t)row1 * ldb + k0 + col1, Bs + c1 * 8);
      __syncthreads();  // compiler drains vmcnt before barrier -> LDS visible

      bf16x8 a[4], b[4];
#pragma unroll
      for (int i = 0; i < 4; i++) {
        a[i] = *(const bf16x8*)(As + (rbm + i) * 512 + fo);
        b[i] = *(const bf16x8*)(Bs + (rbn + i) * 512 + fo);
      }
#pragma unroll
      for (int mi = 0; mi < 4; mi++)
#pragma unroll
        for (int ni = 0; ni < 4; ni++)
          acc[mi][ni] = __builtin_amdgcn_mfma_f32_16x16x32_bf16(
              a[mi], b[ni], acc[mi][ni], 0, 0, 0);
      __syncthreads();  // all waves done reading before next overwrite
    }
  }

  // epilogue: C/D layout col=lane&15, row=(lane>>4)*4+reg
  const int orow = (ln >> 4) * 4;
  const int ocol = ln & 15;
#pragma unroll
  for (int mi = 0; mi < 4; mi++)
#pragma unroll
    for (int ni = 0; ni < 4; ni++) {
      const int rbase = m0 + wm + mi * 16 + orow;
      const int cc = n0 + wn + ni * 16 + ocol;
#pragma unroll
      for (int i = 0; i < 4; i++) {
        const float v = acc[mi][ni][i];
        const long long off =
            (long long)(rbase + i) * ldc + cc + (long long)z * sC;
        if (STORE == 0) {
          Cf[off] = v;
        } else if (STORE == 1) {
          const u16 h = f2bf(v);
          Ch[off] = h;
          Cl[off] = f2bf(v - bf2f(h));
        } else {
          Ch[off] = f2bf(v);
        }
      }
    }
}

// row softmax in place: row of 2048 f32 -> 2048 bf16 over the same storage
// (row byte-stride stays 8192 => P row stride 4096 u16). One block per row.
// All reads happen before the first __syncthreads; writes after the last.
__global__ __launch_bounds__(256) void softmax_inplace(float* __restrict__ L) {
  float* p = L + (size_t)blockIdx.x * 2048;
  const int t = threadIdx.x;
  const int wv = t >> 6, lnn = t & 63;

  float4 x0 = *(const float4*)(p + t * 4);
  float4 x1 = *(const float4*)(p + 1024 + t * 4);

  float m = fmaxf(fmaxf(fmaxf(x0.x, x0.y), fmaxf(x0.z, x0.w)),
                  fmaxf(fmaxf(x1.x, x1.y), fmaxf(x1.z, x1.w)));
#pragma unroll
  for (int off = 32; off; off >>= 1) m = fmaxf(m, __shfl_xor(m, off));
  __shared__ float redm[4];
  __shared__ float reds[4];
  if (lnn == 0) redm[wv] = m;
  __syncthreads();
  m = fmaxf(fmaxf(redm[0], redm[1]), fmaxf(redm[2], redm[3]));

  float e[8];
  e[0] = __expf(x0.x - m); e[1] = __expf(x0.y - m);
  e[2] = __expf(x0.z - m); e[3] = __expf(x0.w - m);
  e[4] = __expf(x1.x - m); e[5] = __expf(x1.y - m);
  e[6] = __expf(x1.z - m); e[7] = __expf(x1.w - m);
  float s = e[0] + e[1] + e[2] + e[3] + e[4] + e[5] + e[6] + e[7];
#pragma unroll
  for (int off = 32; off; off >>= 1) s += __shfl_xor(s, off);
  if (lnn == 0) reds[wv] = s;
  __syncthreads();
  const float inv = 1.f / (reds[0] + reds[1] + reds[2] + reds[3]);

  u16* q = (u16*)p;  // in-place: first 4096 bytes of the 8192-byte row
  ushort4 o0, o1;
  o0.x = f2bf(e[0] * inv); o0.y = f2bf(e[1] * inv);
  o0.z = f2bf(e[2] * inv); o0.w = f2bf(e[3] * inv);
  o1.x = f2bf(e[4] * inv); o1.y = f2bf(e[5] * inv);
  o1.z = f2bf(e[6] * inv); o1.w = f2bf(e[7] * inv);
  *(ushort4*)(q + t * 4) = o0;
  *(ushort4*)(q + 1024 + t * 4) = o1;
}

extern "C" void kernel_launch(void* const* d_in, const int* in_sizes, int n_in,
                              void* d_out, int out_size, void* d_ws, size_t ws_size,
                              hipStream_t stream) {
  constexpr int Bn = 4, S = 2048, D = 1024;
  constexpr long long TOK = (long long)Bn * S;  // 8192
  constexpr long long DD = (long long)D * D;
  const float* X = (const float*)d_in[0];
  const float* Wq = (const float*)d_in[1];
  const float* Wk = (const float*)d_in[2];
  const float* Wv = (const float*)d_in[3];
  float* out = (float*)d_out;
  const dim3 blk(256);

  char* w = (char*)d_ws;
  auto au16 = [&](long long n) { u16* p = (u16*)w; w += n * 2; return p; };

  const bool full = ws_size >= (size_t)196 * 1000 * 1000;  // flat L, G=4
  const bool mid = ws_size >= (size_t)129 * 1000 * 1000;   // aliased L, G=2

  if (full || mid) {
    u16* Xh = au16(TOK * D);
    u16* Xl = au16(TOK * D);
    u16* Wch = au16(2 * DD);  // [Wq;Wk] hi, rows 0-1023 = Wq
    u16* Wcl = au16(2 * DD);
    u16* Wvh = au16(DD);
    u16* QKh = au16(TOK * 2 * D);  // cols 0-1023 = Q, 1024-2047 = K
    u16* QKl = au16(TOK * 2 * D);
    u16* VT = au16((long long)Bn * D * S);
    float* Lf;
    int G;
    if (full) {
      Lf = (float*)w;  // flat, 4*S*S f32
      G = 4;
    } else {
      Lf = (float*)d_ws;  // alias over dead Xh/Xl/W region (42 MiB >= 32 MiB)
      G = 2;
    }

    split_f32_kernel<true><<<2048, blk, 0, stream>>>(X, Xh, Xl, TOK * D);
    split_f32_kernel<true><<<512, blk, 0, stream>>>(Wq, Wch, Wcl, DD);
    split_f32_kernel<true><<<512, blk, 0, stream>>>(Wk, Wch + DD, Wcl + DD, DD);
    split_f32_kernel<false><<<512, blk, 0, stream>>>(Wv, Wvh, nullptr, DD);

    // fused Q|K projection: M=8192, N=2048, 3 segs of K=1024
    gemm_nt<3, 1><<<dim3(16, 64, 1), blk, 0, stream>>>(
        Xh, Xh, Xl, Wch, Wcl, Wch, nullptr, QKh, QKl,
        D, D, D, 2 * D, 0, 0, 0);
    // VT[z][d,s] = Wvh . Xh_z^T : M=1024, N=2048, K=1024, z=4
    gemm_nt<1, 2><<<dim3(16, 8, 4), blk, 0, stream>>>(
        Wvh, nullptr, nullptr, Xh, nullptr, nullptr, nullptr, VT, nullptr,
        D, D, D, S, 0, (long long)S * D, (long long)D * S);

    for (int g = 0; g < Bn / G; ++g) {
      const long long ro = (long long)g * G * S * 2 * D;  // row offset (u16)
      // L[z] = Qh.Kh + Qh.Kl + Ql.Kh : M=N=2048, segs K=1024, z=G
      gemm_nt<3, 0><<<dim3(16, 16, G), blk, 0, stream>>>(
          QKh + ro, QKh + ro, QKl + ro,
          QKh + ro + D, QKl + ro + D, QKh + ro + D,
          Lf, nullptr, nullptr, D, 2 * D, 2 * D, S,
          (long long)S * 2 * D, (long long)S * 2 * D, (long long)S * S);
      softmax_inplace<<<dim3(G * S), blk, 0, stream>>>(Lf);
      // O[z] = P . VT^T : M=2048, N=1024, K=2048
      gemm_nt<1, 0><<<dim3(8, 16, G), blk, 0, stream>>>(
          (const u16*)Lf, nullptr, nullptr, VT + (long long)g * G * D * S,
          nullptr, nullptr, out + (long long)g * G * S * D, nullptr, nullptr,
          S, 2 * S, S, D,
          (long long)S * S * 2, (long long)D * S, (long long)S * D);
    }
  } else {
    // Low tier (~82 MB): per-batch attention buffers
    u16* Xh = au16(TOK * D);
    u16* Xl = au16(TOK * D);
    u16* Wch = au16(2 * DD);
    u16* Wcl = au16(2 * DD);
    u16* Wvh = au16(DD);
    u16* QKhb = au16((long long)S * 2 * D);
    u16* QKlb = au16((long long)S * 2 * D);
    u16* VTb = au16((long long)D * S);
    float* Lb = (float*)w;

    split_f32_kernel<true><<<2048, blk, 0, stream>>>(X, Xh, Xl, TOK * D);
    split_f32_kernel<true><<<512, blk, 0, stream>>>(Wq, Wch, Wcl, DD);
    split_f32_kernel<true><<<512, blk, 0, stream>>>(Wk, Wch + DD, Wcl + DD, DD);
    split_f32_kernel<false><<<512, blk, 0, stream>>>(Wv, Wvh, nullptr, DD);

    for (int b = 0; b < Bn; ++b) {
      const long long xo = (long long)b * S * D;
      gemm_nt<3, 1><<<dim3(16, 16, 1), blk, 0, stream>>>(
          Xh + xo, Xh + xo, Xl + xo, Wch, Wcl, Wch, nullptr, QKhb, QKlb,
          D, D, D, 2 * D, 0, 0, 0);
      gemm_nt<1, 2><<<dim3(16, 8, 1), blk, 0, stream>>>(
          Wvh, nullptr, nullptr, Xh + xo, nullptr, nullptr, nullptr, VTb,
          nullptr, D, D, D, S, 0, 0, 0);
      gemm_nt<3, 0><<<dim3(16, 16, 1), blk, 0, stream>>>(
          QKhb, QKhb, QKlb, QKhb + D, QKlb + D, QKhb + D,
          Lb, nullptr, nullptr, D, 2 * D, 2 * D, S, 0, 0, 0);
      softmax_inplace<<<dim3(S), blk, 0, stream>>>(Lb);
      gemm_nt<1, 0><<<dim3(8, 16, 1), blk, 0, stream>>>(
          (const u16*)Lb, nullptr, nullptr, VTb, nullptr, nullptr,
          out + xo, nullptr, nullptr, S, 2 * S, S, D, 0, 0, 0);
    }
  }
}

// Round 4
// 519.860 us; speedup vs baseline: 4.7040x; 1.1351x over previous
//
#include <hip/hip_runtime.h>
#include <math.h>

// SelfAttention B=4,S=2048,D=1024 fp32. Round 4: 256^2-tile counted-vmcnt GEMM.
// GEMM: NT over NSEG K-segments, C[m,n] = sum_seg sum_k Aseg[m,k]*Bseg[n,k].
// 512 thr = 8 waves (2M x 4N), per-wave 128x64 out, BK=32, 3 LDS buffers
// (32 KB each). Pipeline: group t computes tile t from buf[t%3] while issuing
// stage of tile t+2 into buf[(t+2)%3]; group end = s_waitcnt vmcnt(4) (tile
// t+1 landed, t+2 still flying) + raw s_barrier. Never vmcnt(0) in-loop.

typedef unsigned short u16;
typedef __attribute__((ext_vector_type(8))) short bf16x8;
typedef __attribute__((ext_vector_type(4))) float f32x4;

__device__ __forceinline__ u16 f2bf(float x) {
  unsigned u = __float_as_uint(x);
  unsigned r = (u + 0x7fffu + ((u >> 16) & 1u)) >> 16;
  return (u16)r;
}
__device__ __forceinline__ float bf2f(u16 h) {
  return __uint_as_float((unsigned)h << 16);
}

__device__ __forceinline__ void gload_lds16(const u16* g, u16* l) {
  __builtin_amdgcn_global_load_lds(
      (const __attribute__((address_space(1))) unsigned int*)(g),
      (__attribute__((address_space(3))) unsigned int*)(l), 16, 0, 0);
}

// fp32 -> hi bf16 (+ optional lo bf16), grid-stride, vectorized
template <bool LO>
__global__ __launch_bounds__(256) void split_f32_kernel(
    const float* __restrict__ in, u16* __restrict__ hi, u16* __restrict__ lo,
    long long n) {
  long long i = ((long long)blockIdx.x * 256 + threadIdx.x) * 4;
  const long long step = (long long)gridDim.x * 256 * 4;
  for (; i < n; i += step) {
    float4 x = *(const float4*)(in + i);
    float xs[4] = {x.x, x.y, x.z, x.w};
    u16 hv[4], lv[4];
#pragma unroll
    for (int j = 0; j < 4; j++) {
      hv[j] = f2bf(xs[j]);
      if (LO) lv[j] = f2bf(xs[j] - bf2f(hv[j]));
    }
    ushort4 h;
    h.x = hv[0]; h.y = hv[1]; h.z = hv[2]; h.w = hv[3];
    *(ushort4*)(hi + i) = h;
    if (LO) {
      ushort4 l;
      l.x = lv[0]; l.y = lv[1]; l.z = lv[2]; l.w = lv[3];
      *(ushort4*)(lo + i) = l;
    }
  }
}

// LDS subtile layout per 256x32 tile (16 KB = 8192 u16):
//   elem(row,k) at u16 off (row>>4)*512 + ((k>>3)&3)*128 + (row&15)*8 + (k&7)
// chunk c (16B, c=0..1023): row=((c>>6)<<4)+(c&15), k=((c>>4)&3)*8  (linear dest)
// frag read (16-row block rb): rb*512 + lane*8 -> conflict-free ds_read_b128.
// STORE: 0 = f32 Cf, 1 = split bf16 (Ch,Cl), 2 = bf16 (Ch).
template <int NSEG, int STORE>
__global__ __launch_bounds__(512, 2) void gemm256(
    const u16* __restrict__ A0, const u16* __restrict__ A1,
    const u16* __restrict__ A2, const u16* __restrict__ B0,
    const u16* __restrict__ B1, const u16* __restrict__ B2,
    float* __restrict__ Cf, u16* __restrict__ Ch, u16* __restrict__ Cl,
    int Kseg, int lda, int ldb, int ldc,
    long long sA, long long sB, long long sC) {
  __shared__ u16 lds[3 * 16384];  // 3 bufs x (A 8192 + B 8192) u16 = 96 KB

  const int tid = threadIdx.x;
  const int ln = tid & 63;
  const int wid = tid >> 6;
  const int wm = wid >> 2;   // 0..1 (M half)
  const int wn = wid & 3;    // 0..3 (N quarter)
  const int m0 = blockIdx.y * 256;
  const int n0 = blockIdx.x * 256;
  const int z = blockIdx.z;
  const long long za = (long long)z * sA;
  const long long zb = (long long)z * sB;

  const int c0 = tid, c1 = tid + 512;
  const int r0 = ((c0 >> 6) << 4) + (c0 & 15), k0c = ((c0 >> 4) & 3) * 8;
  const int r1 = ((c1 >> 6) << 4) + (c1 & 15), k1c = ((c1 >> 4) & 3) * 8;

  const int NT = NSEG * (Kseg >> 5);

  f32x4 acc[8][4];
  const f32x4 zero = {0.f, 0.f, 0.f, 0.f};
#pragma unroll
  for (int i = 0; i < 8; i++)
#pragma unroll
    for (int j = 0; j < 4; j++) acc[i][j] = zero;

  auto baseA = [&](int t) -> const u16* {
    int kk = t << 5;
    const u16* p = A0;
    if (NSEG >= 2 && kk >= Kseg) { kk -= Kseg; p = A1; }
    if (NSEG >= 3 && kk >= Kseg) { kk -= Kseg; p = A2; }
    return p + za + (size_t)m0 * lda + kk;
  };
  auto baseB = [&](int t) -> const u16* {
    int kk = t << 5;
    const u16* p = B0;
    if (NSEG >= 2 && kk >= Kseg) { kk -= Kseg; p = B1; }
    if (NSEG >= 3 && kk >= Kseg) { kk -= Kseg; p = B2; }
    return p + zb + (size_t)n0 * ldb + kk;
  };
  auto stage = [&](int t) {
    u16* buf = lds + (t % 3) * 16384;
    const u16* Ab = baseA(t);
    const u16* Bb = baseB(t);
    gload_lds16(Ab + (size_t)r0 * lda + k0c, buf + c0 * 8);
    gload_lds16(Ab + (size_t)r1 * lda + k1c, buf + c1 * 8);
    gload_lds16(Bb + (size_t)r0 * ldb + k0c, buf + 8192 + c0 * 8);
    gload_lds16(Bb + (size_t)r1 * ldb + k1c, buf + 8192 + c1 * 8);
  };

  // prologue: tiles 0,1 in flight; wait tile 0 (4 newest may fly)
  stage(0);
  stage(1);
  asm volatile("s_waitcnt vmcnt(4)" ::: "memory");
  __builtin_amdgcn_s_barrier();
  __builtin_amdgcn_sched_barrier(0);

  for (int t = 0; t < NT; ++t) {
    if (t + 2 < NT) stage(t + 2);  // -> buf[(t+2)%3], freed end of group t-1
    const u16* Abuf = lds + (t % 3) * 16384;
    const u16* Bbuf = Abuf + 8192;
    bf16x8 a[8], b[4];
#pragma unroll
    for (int j = 0; j < 4; ++j)
      b[j] = *(const bf16x8*)(Bbuf + (wn * 4 + j) * 512 + ln * 8);
#pragma unroll
    for (int i = 0; i < 8; ++i)
      a[i] = *(const bf16x8*)(Abuf + (wm * 8 + i) * 512 + ln * 8);
    __builtin_amdgcn_s_setprio(1);
#pragma unroll
    for (int i = 0; i < 8; ++i)
#pragma unroll
      for (int j = 0; j < 4; ++j)
        acc[i][j] = __builtin_amdgcn_mfma_f32_16x16x32_bf16(
            a[i], b[j], acc[i][j], 0, 0, 0);
    __builtin_amdgcn_s_setprio(0);
    if (t + 1 < NT) {
      if (t + 2 < NT) {
        asm volatile("s_waitcnt vmcnt(4)" ::: "memory");  // tile t+1 landed
      } else {
        asm volatile("s_waitcnt vmcnt(0)" ::: "memory");  // drain tail
      }
      __builtin_amdgcn_s_barrier();
      __builtin_amdgcn_sched_barrier(0);
    }
  }

  // epilogue: C/D layout col=lane&15, row=(lane>>4)*4+reg (validated r2/r3)
  const int orow = (ln >> 4) * 4;
  const int ocol = ln & 15;
#pragma unroll
  for (int mi = 0; mi < 8; ++mi)
#pragma unroll
    for (int ni = 0; ni < 4; ++ni) {
      const int rbase = m0 + wm * 128 + mi * 16 + orow;
      const int cc = n0 + wn * 64 + ni * 16 + ocol;
#pragma unroll
      for (int i = 0; i < 4; ++i) {
        const float v = acc[mi][ni][i];
        const long long off =
            (long long)(rbase + i) * ldc + cc + (long long)z * sC;
        if (STORE == 0) {
          Cf[off] = v;
        } else if (STORE == 1) {
          const u16 h = f2bf(v);
          Ch[off] = h;
          Cl[off] = f2bf(v - bf2f(h));
        } else {
          Ch[off] = f2bf(v);
        }
      }
    }
}

// row softmax in place: 2048 f32 -> 2048 bf16 over same storage (row stride
// stays 4096 u16). One block per row.
__global__ __launch_bounds__(256) void softmax_inplace(float* __restrict__ L) {
  float* p = L + (size_t)blockIdx.x * 2048;
  const int t = threadIdx.x;
  const int wv = t >> 6, lnn = t & 63;

  float4 x0 = *(const float4*)(p + t * 4);
  float4 x1 = *(const float4*)(p + 1024 + t * 4);

  float m = fmaxf(fmaxf(fmaxf(x0.x, x0.y), fmaxf(x0.z, x0.w)),
                  fmaxf(fmaxf(x1.x, x1.y), fmaxf(x1.z, x1.w)));
#pragma unroll
  for (int off = 32; off; off >>= 1) m = fmaxf(m, __shfl_xor(m, off));
  __shared__ float redm[4];
  __shared__ float reds[4];
  if (lnn == 0) redm[wv] = m;
  __syncthreads();
  m = fmaxf(fmaxf(redm[0], redm[1]), fmaxf(redm[2], redm[3]));

  float e[8];
  e[0] = __expf(x0.x - m); e[1] = __expf(x0.y - m);
  e[2] = __expf(x0.z - m); e[3] = __expf(x0.w - m);
  e[4] = __expf(x1.x - m); e[5] = __expf(x1.y - m);
  e[6] = __expf(x1.z - m); e[7] = __expf(x1.w - m);
  float s = e[0] + e[1] + e[2] + e[3] + e[4] + e[5] + e[6] + e[7];
#pragma unroll
  for (int off = 32; off; off >>= 1) s += __shfl_xor(s, off);
  if (lnn == 0) reds[wv] = s;
  __syncthreads();
  const float inv = 1.f / (reds[0] + reds[1] + reds[2] + reds[3]);

  u16* q = (u16*)p;
  ushort4 o0, o1;
  o0.x = f2bf(e[0] * inv); o0.y = f2bf(e[1] * inv);
  o0.z = f2bf(e[2] * inv); o0.w = f2bf(e[3] * inv);
  o1.x = f2bf(e[4] * inv); o1.y = f2bf(e[5] * inv);
  o1.z = f2bf(e[6] * inv); o1.w = f2bf(e[7] * inv);
  *(ushort4*)(q + t * 4) = o0;
  *(ushort4*)(q + 1024 + t * 4) = o1;
}

extern "C" void kernel_launch(void* const* d_in, const int* in_sizes, int n_in,
                              void* d_out, int out_size, void* d_ws, size_t ws_size,
                              hipStream_t stream) {
  constexpr int Bn = 4, S = 2048, D = 1024;
  constexpr long long TOK = (long long)Bn * S;  // 8192
  constexpr long long DD = (long long)D * D;
  const float* X = (const float*)d_in[0];
  const float* Wq = (const float*)d_in[1];
  const float* Wk = (const float*)d_in[2];
  const float* Wv = (const float*)d_in[3];
  float* out = (float*)d_out;
  const dim3 blk(256);
  const dim3 gblk(512);

  char* w = (char*)d_ws;
  auto au16 = [&](long long n) { u16* p = (u16*)w; w += n * 2; return p; };

  const bool full = ws_size >= (size_t)196 * 1000 * 1000;
  const bool mid = ws_size >= (size_t)140 * 1000 * 1000;

  if (full || mid) {
    u16* Xh = au16(TOK * D);
    u16* Xl = au16(TOK * D);
    u16* Wch = au16(2 * DD);  // [Wq;Wk] hi
    u16* Wcl = au16(2 * DD);
    u16* Wvh = au16(DD);
    u16* QKh = au16(TOK * 2 * D);  // cols 0..1023 = Q, 1024..2047 = K
    u16* QKl = au16(TOK * 2 * D);
    u16* VTall = au16((long long)D * TOK);  // [D][8192], col = b*2048+s
    float* Lf;
    int G;
    if (full) {
      Lf = (float*)w;  // 4*S*S f32
      G = 4;
    } else {
      Lf = (float*)d_ws;  // alias dead Xh/Xl (33.55 MB >= 2*S*S*4)
      G = 2;
    }

    split_f32_kernel<true><<<2048, blk, 0, stream>>>(X, Xh, Xl, TOK * D);
    split_f32_kernel<true><<<512, blk, 0, stream>>>(Wq, Wch, Wcl, DD);
    split_f32_kernel<true><<<512, blk, 0, stream>>>(Wk, Wch + DD, Wcl + DD, DD);
    split_f32_kernel<false><<<512, blk, 0, stream>>>(Wv, Wvh, nullptr, DD);

    // fused Q|K projection: M=8192, N=2048, segs (Xh,Xh,Xl)x(Wch,Wcl,Wch)
    gemm256<3, 1><<<dim3(8, 32, 1), gblk, 0, stream>>>(
        Xh, Xh, Xl, Wch, Wcl, Wch, nullptr, QKh, QKl,
        D, D, D, 2 * D, 0, 0, 0);
    // VTall[d, t] = Wvh . Xh^T : M=1024, N=8192, K=1024
    gemm256<1, 2><<<dim3(32, 4, 1), gblk, 0, stream>>>(
        Wvh, nullptr, nullptr, Xh, nullptr, nullptr, nullptr, VTall, nullptr,
        D, D, D, (int)TOK, 0, 0, 0);

    for (int g = 0; g < Bn / G; ++g) {
      const long long ro = (long long)g * G * S * 2 * D;  // u16 row offset
      // L[z] = Qh.Kh + Qh.Kl + Ql.Kh : M=N=2048, z=G
      gemm256<3, 0><<<dim3(8, 8, G), gblk, 0, stream>>>(
          QKh + ro, QKh + ro, QKl + ro,
          QKh + ro + D, QKl + ro + D, QKh + ro + D,
          Lf, nullptr, nullptr, D, 2 * D, 2 * D, S,
          (long long)S * 2 * D, (long long)S * 2 * D, (long long)S * S);
      softmax_inplace<<<dim3(G * S), blk, 0, stream>>>(Lf);
      // O[z] = P . VTall(cols b*2048..)^T : M=2048, N=1024, K=2048
      gemm256<1, 0><<<dim3(4, 8, G), gblk, 0, stream>>>(
          (const u16*)Lf, nullptr, nullptr, VTall + (long long)g * G * S,
          nullptr, nullptr, out + (long long)g * G * S * D, nullptr, nullptr,
          S, 2 * S, (int)TOK, D,
          (long long)S * S * 2, (long long)S, (long long)S * D);
    }
  } else {
    // Low tier (~90 MB): per-batch
    u16* Xh = au16(TOK * D);
    u16* Xl = au16(TOK * D);
    u16* Wch = au16(2 * DD);
    u16* Wcl = au16(2 * DD);
    u16* Wvh = au16(DD);
    u16* QKhb = au16((long long)S * 2 * D);
    u16* QKlb = au16((long long)S * 2 * D);
    u16* VTb = au16((long long)D * S);
    float* Lb = (float*)w;

    split_f32_kernel<true><<<2048, blk, 0, stream>>>(X, Xh, Xl, TOK * D);
    split_f32_kernel<true><<<512, blk, 0, stream>>>(Wq, Wch, Wcl, DD);
    split_f32_kernel<true><<<512, blk, 0, stream>>>(Wk, Wch + DD, Wcl + DD, DD);
    split_f32_kernel<false><<<512, blk, 0, stream>>>(Wv, Wvh, nullptr, DD);

    for (int b = 0; b < Bn; ++b) {
      const long long xo = (long long)b * S * D;
      gemm256<3, 1><<<dim3(8, 8, 1), gblk, 0, stream>>>(
          Xh + xo, Xh + xo, Xl + xo, Wch, Wcl, Wch, nullptr, QKhb, QKlb,
          D, D, D, 2 * D, 0, 0, 0);
      gemm256<1, 2><<<dim3(8, 4, 1), gblk, 0, stream>>>(
          Wvh, nullptr, nullptr, Xh + xo, nullptr, nullptr, nullptr, VTb,
          nullptr, D, D, D, S, 0, 0, 0);
      gemm256<3, 0><<<dim3(8, 8, 1), gblk, 0, stream>>>(
          QKhb, QKhb, QKlb, QKhb + D, QKlb + D, QKhb + D,
          Lb, nullptr, nullptr, D, 2 * D, 2 * D, S, 0, 0, 0);
      softmax_inplace<<<dim3(S), blk, 0, stream>>>(Lb);
      gemm256<1, 0><<<dim3(4, 8, 1), gblk, 0, stream>>>(
          (const u16*)Lb, nullptr, nullptr, VTb, nullptr, nullptr,
          out + xo, nullptr, nullptr, S, 2 * S, S, D, 0, 0, 0);
    }
  }
}